// Round 7
// baseline (453.987 us; speedup 1.0000x reference)
//
#include <hip/hip_runtime.h>

// MSPushPullLoss: B=16, C=16, labels 0..16.
// R9: single fused kernel (hist -> device barrier -> mean table -> pull -> last-block
//     finalize). Non-kernel time has been ~75-95us across 3-5 dispatch configs
//     (~15-20us/graph node) -- now the largest line item. Cooperative launch API fails
//     under capture (R5), so: plain launch + resident-set guarantee
//     (1344 blocks <= 256CU x 6 blocks/CU via launch_bounds(256,6)) + hand-rolled
//     hierarchical barrier (21 leaves x 64 + root, 128B-padded counters; single-line
//     arrival measured ~50us in R7 -- avoided).
//     Phase bodies verbatim from R8 (passed): select-histogram + u8x4 label pack,
//     per-block mean/inv table (R7-proven), packed pull, hierarchical last-block finalize.

#define M_VAR 0.1f
#define TWO_M_DIST 3.0f

#define SUB0 64
#define SUB1 16
#define SUB2 4
#define PER_BATCH (SUB0 + SUB1 + SUB2)        // 84
#define NBATCH 16
#define GRID_BLOCKS (NBATCH * PER_BATCH)      // 1344 <= 256 CU * 6 blocks/CU = 1536
#define NITER 16
#define NLEAF 21                              // 1344 / 64 exactly

// dword offsets in ws
#define OFF_PSUM  0                           // [1344][16] per-block label sums
#define OFF_PCNT  (GRID_BLOCKS * 16)          // [1344][16] per-block label counts
#define OFF_PULL  (2 * GRID_BLOCKS * 16)      // [1344] per-block pull partials
#define OFF_GMEAN (OFF_PULL + GRID_BLOCKS)    // [16][16] per-(batch,label) mean
#define OFF_GCNT  (OFF_GMEAN + 256)           // [16][16] per-(batch,label) total count
#define OFF_CTR   (OFF_GCNT + 256)            // 44 counters, 32-dword (128B) stride
#define OFF_PLAB  (OFF_CTR + 44 * 32)         // packed u8x4 labels
#define PLAB_BASE1 (16 * 262144)
#define PLAB_BASE2 (PLAB_BASE1 + 16 * 65536)
#define PLAB_TOTAL (PLAB_BASE2 + 16 * 16384)  // 5505024 dwords
#define WS_NEEDED  ((size_t)(OFF_PLAB + PLAB_TOTAL) * 4)   // ~22.2 MiB
#define WS_MIN_UNPACKED ((size_t)OFF_PLAB * 4)

// counter indices (x32 dwords): [0..20] barrier leaves, [21] barrier root,
//                               [22..42] finalize leaves, [43] finalize root
#define CTR_B_LEAF 0
#define CTR_B_ROOT 21
#define CTR_F_LEAF 22
#define CTR_F_ROOT 43

__device__ __forceinline__ unsigned atom_inc_agent(unsigned* p) {
  return __hip_atomic_fetch_add(p, 1u, __ATOMIC_ACQ_REL, __HIP_MEMORY_SCOPE_AGENT);
}

struct Sel {
  const float4* f; const int4* g;
  int vbase, stride, batch, j, pbase;
};

__device__ __forceinline__ Sel pick(
    int bid, int t,
    const float4* f0, const int4* g0,
    const float4* f1, const int4* g1,
    const float4* f2, const int4* g2) {
  Sel s;
  s.batch = bid / PER_BATCH;
  s.j = bid - s.batch * PER_BATCH;
  if (s.j < SUB0) {
    s.f = f0; s.g = g0; s.pbase = 0;
    s.vbase = s.batch * 262144 + s.j * 256 + t;             s.stride = SUB0 * 256;
  } else if (s.j < SUB0 + SUB1) {
    s.f = f1; s.g = g1; s.pbase = PLAB_BASE1; int sub = s.j - SUB0;
    s.vbase = s.batch * 65536 + sub * 256 + t;              s.stride = SUB1 * 256;
  } else {
    s.f = f2; s.g = g2; s.pbase = PLAB_BASE2; int sub = s.j - SUB0 - SUB1;
    s.vbase = s.batch * 16384 + sub * 256 + t;              s.stride = SUB2 * 256;
  }
  return s;
}

template <bool PACKED>
__global__ __launch_bounds__(256, 6) void fused_kernel(
    const float4* __restrict__ f0, const int4* __restrict__ g0,
    const float4* __restrict__ f1, const int4* __restrict__ g1,
    const float4* __restrict__ f2, const int4* __restrict__ g2,
    float* __restrict__ ws, unsigned* __restrict__ plab,
    float* __restrict__ out)
{
  const int t = threadIdx.x, bid = blockIdx.x;
  Sel s = pick(bid, t, f0, g0, f1, g1, f2, g2);
  unsigned* ctr = (unsigned*)(ws + OFF_CTR);

  // ================= phase A: histogram partials (+ label pack) =================
  {
    float sum[16]; int cnt[16];
    #pragma unroll
    for (int l = 0; l < 16; ++l) { sum[l] = 0.f; cnt[l] = 0; }

    int v = s.vbase;
    float4 fA = s.f[v];            int4 gA = s.g[v];
    float4 fB = s.f[v + s.stride]; int4 gB = s.g[v + s.stride];

    #pragma unroll 1
    for (int it = 0; it < NITER; ++it) {
      int vp = (it + 2 < NITER) ? (v + 2 * s.stride) : v;
      float4 fC = s.f[vp];
      int4   gC = s.g[vp];

      #pragma unroll
      for (int l = 0; l < 16; ++l) {
        bool cx = (gA.x == l + 1); sum[l] += cx ? fA.x : 0.f; cnt[l] += cx;
        bool cy = (gA.y == l + 1); sum[l] += cy ? fA.y : 0.f; cnt[l] += cy;
        bool cz = (gA.z == l + 1); sum[l] += cz ? fA.z : 0.f; cnt[l] += cz;
        bool cw = (gA.w == l + 1); sum[l] += cw ? fA.w : 0.f; cnt[l] += cw;
      }
      if (PACKED) {
        unsigned lx = min((unsigned)gA.x, 16u), ly = min((unsigned)gA.y, 16u);
        unsigned lz = min((unsigned)gA.z, 16u), lw = min((unsigned)gA.w, 16u);
        plab[s.pbase + v] = lx | (ly << 8) | (lz << 16) | (lw << 24);
      }
      fA = fB; gA = gB; fB = fC; gB = gC;
      v += s.stride;
    }

    __shared__ float rs[4][16];
    __shared__ float rc[4][16];
    const int lane = t & 63, wave = t >> 6;
    #pragma unroll
    for (int l = 0; l < 16; ++l) {
      float sv = sum[l];
      float cv = (float)cnt[l];
      #pragma unroll
      for (int o = 32; o > 0; o >>= 1) {
        sv += __shfl_down(sv, o);
        cv += __shfl_down(cv, o);
      }
      if (lane == 0) { rs[wave][l] = sv; rc[wave][l] = cv; }
    }
    __syncthreads();
    if (t < 16) {
      ws[OFF_PSUM + bid * 16 + t] = rs[0][t] + rs[1][t] + rs[2][t] + rs[3][t];
      ws[OFF_PCNT + bid * 16 + t] = rc[0][t] + rc[1][t] + rc[2][t] + rc[3][t];
    }
  }

  // ================= device-wide barrier (hierarchical, padded counters) =========
  if (t == 0) {
    __threadfence();                                 // release my partials (agent)
    unsigned old = atom_inc_agent(&ctr[(CTR_B_LEAF + (bid >> 6)) * 32]);
    if (old == 63) atom_inc_agent(&ctr[CTR_B_ROOT * 32]);
    while (__hip_atomic_load(&ctr[CTR_B_ROOT * 32], __ATOMIC_ACQUIRE,
                             __HIP_MEMORY_SCOPE_AGENT) < (unsigned)NLEAF)
      __builtin_amdgcn_s_sleep(2);
  }
  __syncthreads();

  // ================= phase B prologue: my batch's {mean, inv_cnt} table ==========
  const int myscale = (s.j < SUB0) ? 0 : ((s.j < SUB0 + SUB1) ? 1 : 2);
  __shared__ float ls[16][16], lc[16][16], lm[16][16];   // [k][label]
  __shared__ float2 s_mi[17];
  {
    const int label = t & 15, k = t >> 4;
    float ts = 0.f, tc = 0.f, mc = 0.f;
    const float* psum = ws + OFF_PSUM + s.batch * PER_BATCH * 16;
    const float* pcnt = ws + OFF_PCNT + s.batch * PER_BATCH * 16;
    for (int jj = k; jj < PER_BATCH; jj += 16) {
      float sv = psum[jj * 16 + label];
      float cv = pcnt[jj * 16 + label];
      ts += sv; tc += cv;
      int js = (jj < SUB0) ? 0 : ((jj < SUB0 + SUB1) ? 1 : 2);
      mc += (js == myscale) ? cv : 0.f;
    }
    ls[k][label] = ts; lc[k][label] = tc; lm[k][label] = mc;
  }
  __syncthreads();
  if (t == 0) s_mi[0] = make_float2(0.f, 0.f);  // label 0: contributes nothing
  if (t < 16) {
    float ts = 0.f, tc = 0.f, mc = 0.f;
    #pragma unroll 1
    for (int k = 0; k < 16; ++k) { ts += ls[k][t]; tc += lc[k][t]; mc += lm[k][t]; }
    float mean = ts / fmaxf(tc, 1.f);
    s_mi[1 + t] = make_float2(mean, (mc > 0.f) ? (1.f / mc) : 0.f);
    if (s.j == 0) {                       // one writer per batch for finalize
      ws[OFF_GMEAN + s.batch * 16 + t] = mean;
      ws[OFF_GCNT  + s.batch * 16 + t] = tc;
    }
  }
  __syncthreads();

  // ================= phase B: pull loop =================
  float acc = 0.f;
  {
    int v = s.vbase;
    if (PACKED) {
      float4  fA = s.f[v];               unsigned pA = plab[s.pbase + v];
      float4  fB = s.f[v + s.stride];    unsigned pB = plab[s.pbase + v + s.stride];
      #pragma unroll 1
      for (int it = 0; it < NITER; ++it) {
        int vp = (it + 2 < NITER) ? (v + 2 * s.stride) : v;
        float4   fC = s.f[vp];
        unsigned pC = plab[s.pbase + vp];
        {
          float2 a = s_mi[pA & 255u];
          float d = fmaxf(fabsf(fA.x - a.x) - M_VAR, 0.f); acc += d * d * a.y;
        }
        {
          float2 a = s_mi[(pA >> 8) & 255u];
          float d = fmaxf(fabsf(fA.y - a.x) - M_VAR, 0.f); acc += d * d * a.y;
        }
        {
          float2 a = s_mi[(pA >> 16) & 255u];
          float d = fmaxf(fabsf(fA.z - a.x) - M_VAR, 0.f); acc += d * d * a.y;
        }
        {
          float2 a = s_mi[pA >> 24];
          float d = fmaxf(fabsf(fA.w - a.x) - M_VAR, 0.f); acc += d * d * a.y;
        }
        fA = fB; pA = pB; fB = fC; pB = pC;
        v += s.stride;
      }
    } else {
      float4 fA = s.f[v];            int4 gA = s.g[v];
      float4 fB = s.f[v + s.stride]; int4 gB = s.g[v + s.stride];
      #pragma unroll 1
      for (int it = 0; it < NITER; ++it) {
        int vp = (it + 2 < NITER) ? (v + 2 * s.stride) : v;
        float4 fC = s.f[vp];
        int4   gC = s.g[vp];
        {
          float2 a = s_mi[min((unsigned)gA.x, 16u)];
          float d = fmaxf(fabsf(fA.x - a.x) - M_VAR, 0.f); acc += d * d * a.y;
        }
        {
          float2 a = s_mi[min((unsigned)gA.y, 16u)];
          float d = fmaxf(fabsf(fA.y - a.x) - M_VAR, 0.f); acc += d * d * a.y;
        }
        {
          float2 a = s_mi[min((unsigned)gA.z, 16u)];
          float d = fmaxf(fabsf(fA.z - a.x) - M_VAR, 0.f); acc += d * d * a.y;
        }
        {
          float2 a = s_mi[min((unsigned)gA.w, 16u)];
          float d = fmaxf(fabsf(fA.w - a.x) - M_VAR, 0.f); acc += d * d * a.y;
        }
        fA = fB; gA = gB; fB = fC; gB = gC;
        v += s.stride;
      }
    }
  }
  #pragma unroll
  for (int o = 32; o > 0; o >>= 1) acc += __shfl_down(acc, o);
  __shared__ float racc[4];
  if ((t & 63) == 0) racc[t >> 6] = acc;
  __syncthreads();
  if (t == 0) ws[OFF_PULL + bid] = racc[0] + racc[1] + racc[2] + racc[3];

  // ================= finalize arrival (hierarchical, last block finalizes) =======
  __shared__ int s_fin;
  if (t == 0) {
    s_fin = 0;
    __threadfence();                                 // release my pull partial (+GMEAN/GCNT)
    unsigned old = atom_inc_agent(&ctr[(CTR_F_LEAF + (bid >> 6)) * 32]);
    if (old == 63) {
      unsigned r = atom_inc_agent(&ctr[CTR_F_ROOT * 32]);
      if (r == (unsigned)(NLEAF - 1)) s_fin = 1;
    }
  }
  __syncthreads();
  if (!s_fin) return;

  // ---- finalize (single block) ----
  __shared__ float s_mean[256];
  __shared__ float s_pres[256];
  {
    float cval = ws[OFF_GCNT + t];
    s_mean[t] = ws[OFF_GMEAN + t];
    s_pres[t] = (cval > 0.f) ? 1.f : 0.f;
  }
  __syncthreads();

  float pull_v = 0.f;
  for (int i = t; i < GRID_BLOCKS; i += 256) pull_v += ws[OFF_PULL + i];

  float pull_n = s_pres[t];
  float push_v = 0.f, push_n = 0.f;
  {
    int b = t >> 4, ii = t & 15;
    if (s_pres[t] > 0.f) {
      float mi = s_mean[t];
      for (int jj = 0; jj < 16; ++jj) {
        if (jj == ii) continue;
        int sj = (b << 4) | jj;
        if (s_pres[sj] > 0.f) {
          float d = fmaxf(TWO_M_DIST - fabsf(mi - s_mean[sj]), 0.f);
          push_v += d * d; push_n += 1.f;
        }
      }
    }
  }

  #pragma unroll
  for (int o = 32; o > 0; o >>= 1) {
    pull_v += __shfl_down(pull_v, o);
    pull_n += __shfl_down(pull_n, o);
    push_v += __shfl_down(push_v, o);
    push_n += __shfl_down(push_n, o);
  }
  __shared__ float r[4][4];
  int wave = t >> 6;
  if ((t & 63) == 0) { r[wave][0] = pull_v; r[wave][1] = pull_n; r[wave][2] = push_v; r[wave][3] = push_n; }
  __syncthreads();
  if (t == 0) {
    float PV = 0, PN = 0, SV = 0, SN = 0;
    for (int w = 0; w < 4; ++w) { PV += r[w][0]; PN += r[w][1]; SV += r[w][2]; SN += r[w][3]; }
    out[0] = PV / fmaxf(PN, 1.f) + SV / fmaxf(SN, 1.f);
  }
}

extern "C" void kernel_launch(void* const* d_in, const int* in_sizes, int n_in,
                              void* d_out, int out_size, void* d_ws, size_t ws_size,
                              hipStream_t stream) {
  // setup_inputs() dict order: featmap0, gt0, featmap1, gt1, featmap2, gt2
  const float4* f0 = (const float4*)d_in[0];
  const int4*   g0 = (const int4*)  d_in[1];
  const float4* f1 = (const float4*)d_in[2];
  const int4*   g1 = (const int4*)  d_in[3];
  const float4* f2 = (const float4*)d_in[4];
  const int4*   g2 = (const int4*)  d_in[5];
  float*    ws   = (float*)d_ws;
  unsigned* plab = (unsigned*)d_ws + OFF_PLAB;
  float*    out  = (float*)d_out;

  // zero the 44 padded barrier/arrival counters (replay-safe each graph iteration)
  hipMemsetAsync(ws + OFF_CTR, 0, 44 * 32 * sizeof(float), stream);

  if (ws_size >= WS_NEEDED) {
    fused_kernel<true><<<GRID_BLOCKS, 256, 0, stream>>>(
        f0, g0, f1, g1, f2, g2, ws, plab, out);
  } else {
    fused_kernel<false><<<GRID_BLOCKS, 256, 0, stream>>>(
        f0, g0, f1, g1, f2, g2, ws, plab, out);
  }
}

// Round 8
// 219.970 us; speedup vs baseline: 2.0639x; 2.0639x over previous
//
#include <hip/hip_runtime.h>

// MSPushPullLoss: B=16, C=16, labels 0..16.
// R10: back to the R8 4-dispatch skeleton (passed; zero atomics). Fixed harness floor
//      ~85us is dispatch-count-independent (R7 2-disp vs R8 4-disp: same overhead), so
//      optimize SUM of kernel times only.
//  - hist register diet to kill AGPR round-trips (R8: VGPR_Count=32 < live accumulators
//    -> accvgpr traffic doubles VALU): counts nibble-packed in 4 u32 (max 32/field),
//    sums via two-level select tree on (lab-1); ~50 VGPR total.
//  - plab pack dropped (measured net-negative: hist +15us > pull -10us).
//  - contiguous per-block layout: NITER=8, each block streams 32KB/stream sequentially;
//    grid 2688; pull at launch_bounds(256,8) for occupancy.

#define M_VAR 0.1f
#define TWO_M_DIST 3.0f

#define NITER 8
#define ELEMS 2048                          // float4 per block = 256*NITER
#define B0 128                              // 262144/2048 blocks per batch, scale0
#define B1 32                               // 65536/2048
#define B2 8                                // 16384/2048
#define PER_BATCH (B0 + B1 + B2)            // 168
#define NBATCH 16
#define GRID_BLOCKS (NBATCH * PER_BATCH)    // 2688

// dword offsets in ws
#define OFF_PSUM  0                           // [2688][16]
#define OFF_PCNT  (GRID_BLOCKS * 16)          // [2688][16]
#define OFF_MI    (2 * GRID_BLOCKS * 16)      // [3][16][17] float2 {mean, inv_cnt}
#define OFF_GMEAN (OFF_MI + 3 * 16 * 17 * 2)  // [16][16]
#define OFF_GCNT  (OFF_GMEAN + 256)           // [16][16]
#define OFF_PULL  (OFF_GCNT + 256)            // [2688]

struct Sel {
  const float4* f; const int4* g;
  int vbase, batch, j;
};

__device__ __forceinline__ Sel pick(
    int bid, int t,
    const float4* f0, const int4* g0,
    const float4* f1, const int4* g1,
    const float4* f2, const int4* g2) {
  Sel s;
  s.batch = bid / PER_BATCH;
  s.j = bid - s.batch * PER_BATCH;
  if (s.j < B0) {
    s.f = f0; s.g = g0;
    s.vbase = s.batch * 262144 + s.j * ELEMS + t;
  } else if (s.j < B0 + B1) {
    s.f = f1; s.g = g1;
    s.vbase = s.batch * 65536 + (s.j - B0) * ELEMS + t;
  } else {
    s.f = f2; s.g = g2;
    s.vbase = s.batch * 16384 + (s.j - B0 - B1) * ELEMS + t;
  }
  return s;
}

// per-element histogram update: sums via 2-level tree on lm=lab-1; counts nibble-packed
__device__ __forceinline__ void hupd(float f, int g, float* __restrict__ sum,
                                     unsigned* __restrict__ cp, unsigned one) {
  unsigned lm = (unsigned)g - 1u;          // 0..15 valid; background -> 0xFFFFFFFF
  unsigned hi = lm >> 2;                   // matches no r in 0..3 for background
  unsigned lo = lm & 3u;
  float gf0 = (hi == 0u) ? f : 0.f;
  float gf1 = (hi == 1u) ? f : 0.f;
  float gf2 = (hi == 2u) ? f : 0.f;
  float gf3 = (hi == 3u) ? f : 0.f;
  unsigned inc = one << (lo << 3);         // 1 << (lo*8)
  cp[0] += (hi == 0u) ? inc : 0u;
  cp[1] += (hi == 1u) ? inc : 0u;
  cp[2] += (hi == 2u) ? inc : 0u;
  cp[3] += (hi == 3u) ? inc : 0u;
  #pragma unroll
  for (int c = 0; c < 4; ++c) {
    bool mc = (lo == (unsigned)c);
    sum[0 * 4 + c] += mc ? gf0 : 0.f;
    sum[1 * 4 + c] += mc ? gf1 : 0.f;
    sum[2 * 4 + c] += mc ? gf2 : 0.f;
    sum[3 * 4 + c] += mc ? gf3 : 0.f;
  }
}

// ---------------- kernel 1: per-block histogram partials ----------------
__global__ __launch_bounds__(256, 4) void hist_kernel(
    const float4* __restrict__ f0, const int4* __restrict__ g0,
    const float4* __restrict__ f1, const int4* __restrict__ g1,
    const float4* __restrict__ f2, const int4* __restrict__ g2,
    float* __restrict__ ws)
{
  const int t = threadIdx.x, bid = blockIdx.x;
  Sel s = pick(bid, t, f0, g0, f1, g1, f2, g2);

  float sum[16];
  unsigned cp[4];                 // 16 8-bit counters; per-field max 8*4=32 (no overflow)
  #pragma unroll
  for (int l = 0; l < 16; ++l) sum[l] = 0.f;
  #pragma unroll
  for (int r = 0; r < 4; ++r) cp[r] = 0u;
  const unsigned one = 1u;

  int v = s.vbase;
  float4 fA = s.f[v];        int4 gA = s.g[v];
  float4 fB = s.f[v + 256];  int4 gB = s.g[v + 256];

  #pragma unroll 1
  for (int it = 0; it < NITER; ++it) {
    int vp = (it + 2 < NITER) ? (v + 512) : v;
    float4 fC = s.f[vp];
    int4   gC = s.g[vp];

    hupd(fA.x, gA.x, sum, cp, one);
    hupd(fA.y, gA.y, sum, cp, one);
    hupd(fA.z, gA.z, sum, cp, one);
    hupd(fA.w, gA.w, sum, cp, one);

    fA = fB; gA = gB; fB = fC; gB = gC;
    v += 256;
  }

  // unpack counts, then wave shfl-reduce + cross-wave combine
  __shared__ float rs[4][16];
  __shared__ float rc[4][16];
  const int lane = t & 63, wave = t >> 6;
  #pragma unroll
  for (int l = 0; l < 16; ++l) {
    float sv = sum[l];
    float cv = (float)((cp[l >> 2] >> ((l & 3) * 8)) & 255u);
    #pragma unroll
    for (int o = 32; o > 0; o >>= 1) {
      sv += __shfl_down(sv, o);
      cv += __shfl_down(cv, o);
    }
    if (lane == 0) { rs[wave][l] = sv; rc[wave][l] = cv; }
  }
  __syncthreads();
  if (t < 16) {
    ws[OFF_PSUM + bid * 16 + t] = rs[0][t] + rs[1][t] + rs[2][t] + rs[3][t];
    ws[OFF_PCNT + bid * 16 + t] = rc[0][t] + rc[1][t] + rc[2][t] + rc[3][t];
  }
}

// ---------------- kernel 2: per-batch mean/inv tables ----------------
__global__ __launch_bounds__(256) void mean_kernel(float* __restrict__ ws) {
  const int b = blockIdx.x;                    // 16 blocks, one per batch
  const int t = threadIdx.x;
  const int label = t & 15, k = t >> 4;

  float ts = 0.f, tc = 0.f, c0 = 0.f, c1 = 0.f, c2 = 0.f;
  for (int jj = k; jj < PER_BATCH; jj += 16) {
    float sv = ws[OFF_PSUM + (b * PER_BATCH + jj) * 16 + label];
    float cv = ws[OFF_PCNT + (b * PER_BATCH + jj) * 16 + label];
    ts += sv; tc += cv;
    if (jj < B0) c0 += cv; else if (jj < B0 + B1) c1 += cv; else c2 += cv;
  }
  __shared__ float L[5][16][16];               // [{ts,tc,c0,c1,c2}][k][label]
  L[0][k][label] = ts; L[1][k][label] = tc;
  L[2][k][label] = c0; L[3][k][label] = c1; L[4][k][label] = c2;
  __syncthreads();

  float2* mi = (float2*)(ws + OFF_MI);
  if (t < 16) {
    float Ts = 0.f, Tc = 0.f, C0 = 0.f, C1 = 0.f, C2 = 0.f;
    #pragma unroll 1
    for (int kk = 0; kk < 16; ++kk) {
      Ts += L[0][kk][t]; Tc += L[1][kk][t];
      C0 += L[2][kk][t]; C1 += L[3][kk][t]; C2 += L[4][kk][t];
    }
    float mean = Ts / fmaxf(Tc, 1.f);
    ws[OFF_GMEAN + b * 16 + t] = mean;
    ws[OFF_GCNT  + b * 16 + t] = Tc;
    mi[(0 * 16 + b) * 17 + 1 + t] = make_float2(mean, (C0 > 0.f) ? (1.f / C0) : 0.f);
    mi[(1 * 16 + b) * 17 + 1 + t] = make_float2(mean, (C1 > 0.f) ? (1.f / C1) : 0.f);
    mi[(2 * 16 + b) * 17 + 1 + t] = make_float2(mean, (C2 > 0.f) ? (1.f / C2) : 0.f);
  } else if (t == 16) {
    mi[(0 * 16 + b) * 17] = make_float2(0.f, 0.f);   // label 0: contributes nothing
    mi[(1 * 16 + b) * 17] = make_float2(0.f, 0.f);
    mi[(2 * 16 + b) * 17] = make_float2(0.f, 0.f);
  }
}

// ---------------- kernel 3: pure streaming pull loop ----------------
__global__ __launch_bounds__(256, 8) void pull_kernel(
    const float4* __restrict__ f0, const int4* __restrict__ g0,
    const float4* __restrict__ f1, const int4* __restrict__ g1,
    const float4* __restrict__ f2, const int4* __restrict__ g2,
    float* __restrict__ ws)
{
  const int t = threadIdx.x, bid = blockIdx.x;
  Sel s = pick(bid, t, f0, g0, f1, g1, f2, g2);
  const int myscale = (s.j < B0) ? 0 : ((s.j < B0 + B1) ? 1 : 2);

  __shared__ float2 s_mi[17];
  if (t < 17) s_mi[t] = ((const float2*)(ws + OFF_MI))[(myscale * 16 + s.batch) * 17 + t];
  __syncthreads();

  float acc = 0.f;
  int v = s.vbase;
  float4 fA = s.f[v];        int4 gA = s.g[v];
  float4 fB = s.f[v + 256];  int4 gB = s.g[v + 256];

  #pragma unroll 1
  for (int it = 0; it < NITER; ++it) {
    int vp = (it + 2 < NITER) ? (v + 512) : v;
    float4 fC = s.f[vp];
    int4   gC = s.g[vp];
    {
      float2 a = s_mi[min((unsigned)gA.x, 16u)];
      float d = fmaxf(fabsf(fA.x - a.x) - M_VAR, 0.f); acc += d * d * a.y;
    }
    {
      float2 a = s_mi[min((unsigned)gA.y, 16u)];
      float d = fmaxf(fabsf(fA.y - a.x) - M_VAR, 0.f); acc += d * d * a.y;
    }
    {
      float2 a = s_mi[min((unsigned)gA.z, 16u)];
      float d = fmaxf(fabsf(fA.z - a.x) - M_VAR, 0.f); acc += d * d * a.y;
    }
    {
      float2 a = s_mi[min((unsigned)gA.w, 16u)];
      float d = fmaxf(fabsf(fA.w - a.x) - M_VAR, 0.f); acc += d * d * a.y;
    }
    fA = fB; gA = gB; fB = fC; gB = gC;
    v += 256;
  }

  #pragma unroll
  for (int o = 32; o > 0; o >>= 1) acc += __shfl_down(acc, o);
  __shared__ float racc[4];
  if ((t & 63) == 0) racc[t >> 6] = acc;
  __syncthreads();
  if (t == 0) ws[OFF_PULL + bid] = racc[0] + racc[1] + racc[2] + racc[3];
}

// ---------------- kernel 4: finalize ----------------
__global__ __launch_bounds__(256) void finalize_kernel(
    const float* __restrict__ ws, float* __restrict__ out)
{
  const int t = threadIdx.x;
  __shared__ float s_mean[256];
  __shared__ float s_pres[256];
  {
    float cval = ws[OFF_GCNT + t];
    s_mean[t] = ws[OFF_GMEAN + t];
    s_pres[t] = (cval > 0.f) ? 1.f : 0.f;
  }
  __syncthreads();

  float pull_v = 0.f;
  for (int i = t; i < GRID_BLOCKS; i += 256) pull_v += ws[OFF_PULL + i];

  float pull_n = s_pres[t];
  float push_v = 0.f, push_n = 0.f;
  {
    int b = t >> 4, ii = t & 15;
    if (s_pres[t] > 0.f) {
      float mi = s_mean[t];
      for (int jj = 0; jj < 16; ++jj) {
        if (jj == ii) continue;
        int sj = (b << 4) | jj;
        if (s_pres[sj] > 0.f) {
          float d = fmaxf(TWO_M_DIST - fabsf(mi - s_mean[sj]), 0.f);
          push_v += d * d; push_n += 1.f;
        }
      }
    }
  }

  #pragma unroll
  for (int o = 32; o > 0; o >>= 1) {
    pull_v += __shfl_down(pull_v, o);
    pull_n += __shfl_down(pull_n, o);
    push_v += __shfl_down(push_v, o);
    push_n += __shfl_down(push_n, o);
  }
  __shared__ float r[4][4];
  int wave = t >> 6;
  if ((t & 63) == 0) { r[wave][0] = pull_v; r[wave][1] = pull_n; r[wave][2] = push_v; r[wave][3] = push_n; }
  __syncthreads();
  if (t == 0) {
    float PV = 0, PN = 0, SV = 0, SN = 0;
    for (int w = 0; w < 4; ++w) { PV += r[w][0]; PN += r[w][1]; SV += r[w][2]; SN += r[w][3]; }
    out[0] = PV / fmaxf(PN, 1.f) + SV / fmaxf(SN, 1.f);
  }
}

extern "C" void kernel_launch(void* const* d_in, const int* in_sizes, int n_in,
                              void* d_out, int out_size, void* d_ws, size_t ws_size,
                              hipStream_t stream) {
  // setup_inputs() dict order: featmap0, gt0, featmap1, gt1, featmap2, gt2
  const float4* f0 = (const float4*)d_in[0];
  const int4*   g0 = (const int4*)  d_in[1];
  const float4* f1 = (const float4*)d_in[2];
  const int4*   g1 = (const int4*)  d_in[3];
  const float4* f2 = (const float4*)d_in[4];
  const int4*   g2 = (const int4*)  d_in[5];
  float* ws  = (float*)d_ws;
  float* out = (float*)d_out;

  hist_kernel<<<GRID_BLOCKS, 256, 0, stream>>>(f0, g0, f1, g1, f2, g2, ws);
  mean_kernel<<<NBATCH, 256, 0, stream>>>(ws);
  pull_kernel<<<GRID_BLOCKS, 256, 0, stream>>>(f0, g0, f1, g1, f2, g2, ws);
  finalize_kernel<<<1, 256, 0, stream>>>(ws, out);
}